// Round 4
// baseline (1094.278 us; speedup 1.0000x reference)
//
#include <hip/hip_runtime.h>

#define N_NODES 65536
#define N_EDGES 1048576
#define N_LABEL 2097152
#define DIM_IN 32
#define DIM_H 64
#define NSLAB 4
#define SLAB_SHIFT 14              // src >> 14 -> slab (16384 nodes = 4 MB of 64-dim fp32)
#define SCAN_L (NSLAB * N_NODES)   // 262144 counters

// ---------------- CSR build ([slab][dst]-bucketed) ----------------

__global__ void k_init(float* __restrict__ deg, int* __restrict__ cnt2) {
    int i = blockIdx.x * blockDim.x + threadIdx.x;  // SCAN_L threads
    cnt2[i] = 0;
    if (i < N_NODES) deg[i] = 1.0f;  // self-loop weight
}

__global__ void k_cnt(const int* __restrict__ ei, const float* __restrict__ w,
                      int* __restrict__ cnt2, float* __restrict__ deg) {
    int e = blockIdx.x * blockDim.x + threadIdx.x;
    int s = ei[e];
    int d = ei[N_EDGES + e];
    atomicAdd(&cnt2[(s >> SLAB_SHIFT) * N_NODES + d], 1);
    atomicAdd(&deg[d], w[e]);
}

// 3-kernel exclusive scan over cnt2[SCAN_L] -> offs2 (+ sentinel), cursor2
__global__ void k_scan1(const int* __restrict__ cnt2, int* __restrict__ blksum) {
    int tid = threadIdx.x;
    const int4* p = (const int4*)(cnt2 + blockIdx.x * 1024);
    int4 v = p[tid];
    int s = v.x + v.y + v.z + v.w;
    for (int d = 1; d < 64; d <<= 1) s += __shfl_xor(s, d);
    __shared__ int ws[4];
    if ((tid & 63) == 0) ws[tid >> 6] = s;
    __syncthreads();
    if (tid == 0) blksum[blockIdx.x] = ws[0] + ws[1] + ws[2] + ws[3];
}

__global__ void k_scan2(int* __restrict__ blksum) {
    __shared__ int sh[256];
    int tid = threadIdx.x;
    sh[tid] = blksum[tid];
    __syncthreads();
    if (tid == 0) {
        int run = 0;
        for (int i = 0; i < 256; ++i) { int t = sh[i]; sh[i] = run; run += t; }
    }
    __syncthreads();
    blksum[tid] = sh[tid];
}

__global__ void k_scan3(const int* __restrict__ cnt2, const int* __restrict__ blksum,
                        int* __restrict__ offs2, int* __restrict__ cursor2) {
    int tid = threadIdx.x, bid = blockIdx.x;
    const int4* p = (const int4*)(cnt2 + bid * 1024);
    int4 v = p[tid];
    int s = v.x + v.y + v.z + v.w;
    int lane = tid & 63, wid = tid >> 6;
    int sc = s;
    for (int d = 1; d < 64; d <<= 1) {
        int t = __shfl_up(sc, d);
        if (lane >= d) sc += t;
    }
    __shared__ int ws[4];
    if (lane == 63) ws[wid] = sc;
    __syncthreads();
    int base = blksum[bid];
    for (int w = 0; w < wid; ++w) base += ws[w];
    int ex = base + sc - s;  // exclusive prefix of this thread's 4 entries
    int idx = bid * 1024 + tid * 4;
    int o0 = ex, o1 = o0 + v.x, o2 = o1 + v.y, o3 = o2 + v.z;
    offs2[idx] = o0; offs2[idx + 1] = o1; offs2[idx + 2] = o2; offs2[idx + 3] = o3;
    cursor2[idx] = o0; cursor2[idx + 1] = o1; cursor2[idx + 2] = o2; cursor2[idx + 3] = o3;
    if (bid == 255 && tid == 255) offs2[SCAN_L] = o3 + v.w;  // == N_EDGES
}

__global__ void k_dinv(float* __restrict__ deg) {
    int v = blockIdx.x * blockDim.x + threadIdx.x;
    deg[v] = rsqrtf(deg[v]);
}

__global__ void k_fill(const int* __restrict__ ei, const float* __restrict__ w,
                       const float* __restrict__ dinv, int* __restrict__ cursor2,
                       int* __restrict__ csr_src, float* __restrict__ csr_nrm) {
    int e = blockIdx.x * blockDim.x + threadIdx.x;
    int s = ei[e];
    int d = ei[N_EDGES + e];
    int pos = atomicAdd(&cursor2[(s >> SLAB_SHIFT) * N_NODES + d], 1);
    csr_src[pos] = s;
    csr_nrm[pos] = dinv[s] * w[e] * dinv[d];
}

// ---------------- slab pass: partial aggregation (+ transform on last pass) ----------------
// One 64-lane wave per node. offs2s = offs2 + slab*N_NODES (contiguous global scan, so
// offs2s[v+1] is the correct end even at slab boundaries; offs2[SCAN_L] = E sentinel).
// Partial K-dim sums live in the first K floats of dst's 64-float row.

template <int K, bool FIRST, bool LAST, bool RELU>
__global__ void __launch_bounds__(256) k_pass(
        const int* __restrict__ offs2s, const int* __restrict__ csr_src,
        const float* __restrict__ csr_nrm, const float* __restrict__ h,
        const float* __restrict__ dinv, const float* __restrict__ W,
        const float* __restrict__ b, float* __restrict__ dst) {
    __shared__ float Wl[LAST ? K * 64 : 1];
    int tid = threadIdx.x;
    if (LAST) {
        for (int i = tid; i < K * 64; i += 256) Wl[i] = W[i];
        __syncthreads();
    }

    int v = blockIdx.x * 4 + (tid >> 6);
    int lane = tid & 63;
    int k = lane & (K - 1);

    float acc;
    if (FIRST) {
        float dv = dinv[v];
        acc = dv * dv * h[(size_t)v * K + k];  // self-loop
    } else {
        acc = dst[(size_t)v * 64 + k];         // partial from previous passes
    }

    int j0 = __builtin_amdgcn_readfirstlane(offs2s[v]);
    int j1 = __builtin_amdgcn_readfirstlane(offs2s[v + 1]);
    int j = j0;
    for (; j + 4 <= j1; j += 4) {
        int s0 = __builtin_amdgcn_readfirstlane(csr_src[j + 0]);
        int s1 = __builtin_amdgcn_readfirstlane(csr_src[j + 1]);
        int s2 = __builtin_amdgcn_readfirstlane(csr_src[j + 2]);
        int s3 = __builtin_amdgcn_readfirstlane(csr_src[j + 3]);
        float n0 = csr_nrm[j + 0], n1 = csr_nrm[j + 1];
        float n2 = csr_nrm[j + 2], n3 = csr_nrm[j + 3];
        float r0 = h[(size_t)s0 * K + k];
        float r1 = h[(size_t)s1 * K + k];
        float r2 = h[(size_t)s2 * K + k];
        float r3 = h[(size_t)s3 * K + k];
        acc += n0 * r0; acc += n1 * r1; acc += n2 * r2; acc += n3 * r3;
    }
    for (; j < j1; ++j) {
        int s = __builtin_amdgcn_readfirstlane(csr_src[j]);
        acc += csr_nrm[j] * h[(size_t)s * K + k];
    }

    if (!LAST) {
        if (lane < K) dst[(size_t)v * 64 + k] = acc;
    } else {
        // o[lane] = sum_k acc[k] * W[k][lane] + b[lane]
        float o0 = 0.f, o1 = 0.f, o2 = 0.f, o3 = 0.f;
#pragma unroll
        for (int kk = 0; kk < K; kk += 4) {
            o0 += __shfl(acc, kk + 0) * Wl[(kk + 0) * 64 + lane];
            o1 += __shfl(acc, kk + 1) * Wl[(kk + 1) * 64 + lane];
            o2 += __shfl(acc, kk + 2) * Wl[(kk + 2) * 64 + lane];
            o3 += __shfl(acc, kk + 3) * Wl[(kk + 3) * 64 + lane];
        }
        float o = (o0 + o1) + (o2 + o3) + b[lane];
        if (RELU) o = fmaxf(o, 0.f);
        dst[(size_t)v * 64 + lane] = o;
    }
}

// ---------------- decode: out[p] = dot(enc[a], enc[b]) ----------------

__global__ void k_decode(const int* __restrict__ eli, const float4* __restrict__ enc4,
                         float* __restrict__ out) {
    int gid = blockIdx.x * blockDim.x + threadIdx.x;  // EL*16 threads
    int p = gid >> 4;
    int c4 = gid & 15;
    int a = eli[p];
    int b = eli[N_LABEL + p];
    float4 ea = enc4[(size_t)a * 16 + c4];
    float4 eb = enc4[(size_t)b * 16 + c4];
    float s = ea.x * eb.x + ea.y * eb.y + ea.z * eb.z + ea.w * eb.w;
#pragma unroll
    for (int m = 8; m >= 1; m >>= 1) s += __shfl_xor(s, m, 16);
    if (c4 == 0) out[p] = s;
}

// ---------------- host ----------------

template <int K, bool RELU>
static void launch_layer(const int* offs2, const int* csr_src, const float* csr_nrm,
                         const float* h, const float* dinv, const float* W,
                         const float* b, float* dst, hipStream_t stream) {
    const int g = N_NODES / 4;
    k_pass<K, true,  false, false><<<g, 256, 0, stream>>>(offs2 + 0 * N_NODES, csr_src, csr_nrm, h, dinv, W, b, dst);
    k_pass<K, false, false, false><<<g, 256, 0, stream>>>(offs2 + 1 * N_NODES, csr_src, csr_nrm, h, dinv, W, b, dst);
    k_pass<K, false, false, false><<<g, 256, 0, stream>>>(offs2 + 2 * N_NODES, csr_src, csr_nrm, h, dinv, W, b, dst);
    k_pass<K, false, true,  RELU ><<<g, 256, 0, stream>>>(offs2 + 3 * N_NODES, csr_src, csr_nrm, h, dinv, W, b, dst);
}

extern "C" void kernel_launch(void* const* d_in, const int* in_sizes, int n_in,
                              void* d_out, int out_size, void* d_ws, size_t ws_size,
                              hipStream_t stream) {
    const float* x   = (const float*)d_in[0];
    const int*   ei  = (const int*)d_in[1];
    const float* ew  = (const float*)d_in[2];
    const int*   eli = (const int*)d_in[3];
    const float* W[6] = {(const float*)d_in[4],  (const float*)d_in[6],
                         (const float*)d_in[8],  (const float*)d_in[10],
                         (const float*)d_in[12], (const float*)d_in[14]};
    const float* B[6] = {(const float*)d_in[5],  (const float*)d_in[7],
                         (const float*)d_in[9],  (const float*)d_in[11],
                         (const float*)d_in[13], (const float*)d_in[15]};

    char* ws = (char*)d_ws;
    float* dinv    = (float*)ws;  ws += N_NODES * 4;
    int*   cnt2    = (int*)ws;    ws += SCAN_L * 4;
    int*   cursor2 = (int*)ws;    ws += SCAN_L * 4;
    int*   offs2   = (int*)ws;    ws += (SCAN_L + 16) * 4;
    int*   blksum  = (int*)ws;    ws += 256 * 4;
    int*   csr_src = (int*)ws;    ws += N_EDGES * 4;
    float* csr_nrm = (float*)ws;  ws += N_EDGES * 4;
    float* bufA    = (float*)ws;  ws += (size_t)N_NODES * 64 * 4;
    float* bufB    = (float*)ws;

    const int BS = 256;

    // CSR build + norm
    k_init <<<SCAN_L / BS, BS, 0, stream>>>(dinv, cnt2);
    k_cnt  <<<N_EDGES / BS, BS, 0, stream>>>(ei, ew, cnt2, dinv);
    k_scan1<<<256, BS, 0, stream>>>(cnt2, blksum);
    k_scan2<<<1, BS, 0, stream>>>(blksum);
    k_scan3<<<256, BS, 0, stream>>>(cnt2, blksum, offs2, cursor2);
    k_dinv <<<N_NODES / BS, BS, 0, stream>>>(dinv);
    k_fill <<<N_EDGES / BS, BS, 0, stream>>>(ei, ew, dinv, cursor2, csr_src, csr_nrm);

    // fused layers (4 slab passes each)
    launch_layer<DIM_IN, true >(offs2, csr_src, csr_nrm, x,    dinv, W[0], B[0], bufA, stream);
    launch_layer<DIM_H,  true >(offs2, csr_src, csr_nrm, bufA, dinv, W[1], B[1], bufB, stream);
    launch_layer<DIM_H,  true >(offs2, csr_src, csr_nrm, bufB, dinv, W[2], B[2], bufA, stream);
    launch_layer<DIM_H,  true >(offs2, csr_src, csr_nrm, bufA, dinv, W[3], B[3], bufB, stream);
    launch_layer<DIM_H,  true >(offs2, csr_src, csr_nrm, bufB, dinv, W[4], B[4], bufA, stream);
    launch_layer<DIM_H,  false>(offs2, csr_src, csr_nrm, bufA, dinv, W[5], B[5], bufB, stream);

    // decode
    k_decode<<<N_LABEL * 16 / BS, BS, 0, stream>>>(eli, (const float4*)bufB, (float*)d_out);
}